// Round 11
// baseline (551.994 us; speedup 1.0000x reference)
//
#include <hip/hip_runtime.h>
#include <math.h>

#define N_NODES   10000
#define N_EDGES   320000
#define IN_DIM    128
#define HIDDEN    256
#define NUM_LAYERS 6
#define ALPHA     0.1f
#define LN_EPS    1e-5f

__device__ __forceinline__ float gelu_exact(float x) {
    // jax.nn.gelu(approximate=False): 0.5*x*(1+erf(x/sqrt(2)))
    return 0.5f * x * (1.0f + erff(x * 0.70710678118654752440f));
}

__device__ __forceinline__ float wave_sum64(float v) {
#pragma unroll
    for (int i = 32; i > 0; i >>= 1) v += __shfl_xor(v, i);
    return v;
}

// ---------------- graph preprocessing ----------------

__global__ __launch_bounds__(256) void count_deg_kernel(const int* __restrict__ dst,
                                                        int* __restrict__ cnt) {
    int e = blockIdx.x * 256 + threadIdx.x;
    if (e < N_EDGES) atomicAdd(&cnt[dst[e]], 1);
}

__global__ __launch_bounds__(256) void dinv_kernel(const int* __restrict__ cnt,
                                                   float* __restrict__ dinv) {
    int i = blockIdx.x * 256 + threadIdx.x;
    // +1 for the self loop; deg >= 1 always so the deg>0 guard is moot
    if (i < N_NODES) dinv[i] = rsqrtf((float)(cnt[i] + 1));
}

// single-block exclusive scan over 10000 counts -> CSR row offsets
__global__ __launch_bounds__(256) void scan_kernel(const int* __restrict__ cnt,
                                                   int* __restrict__ offs) {
    __shared__ int sums[256];
    __shared__ int bases[257];
    int t = threadIdx.x;
    const int chunk = (N_NODES + 255) / 256;  // 40
    int b0 = t * chunk;
    int b1 = b0 + chunk; if (b1 > N_NODES) b1 = N_NODES;
    if (b0 > N_NODES) b0 = N_NODES;
    int s = 0;
    for (int i = b0; i < b1; ++i) s += cnt[i];
    sums[t] = s;
    __syncthreads();
    if (t == 0) {
        int r = 0;
        for (int i = 0; i < 256; ++i) { bases[i] = r; r += sums[i]; }
        bases[256] = r;
    }
    __syncthreads();
    int r = bases[t];
    for (int i = b0; i < b1; ++i) { offs[i] = r; r += cnt[i]; }
    if (t == 0) offs[N_NODES] = bases[256];
}

__global__ __launch_bounds__(256) void fill_csr_kernel(const int* __restrict__ src,
                                                       const int* __restrict__ dst,
                                                       const int* __restrict__ offs,
                                                       int* __restrict__ cursor,
                                                       int* __restrict__ csr_src) {
    int e = blockIdx.x * 256 + threadIdx.x;
    if (e < N_EDGES) {
        int d = dst[e], s = src[e];
        int pos = atomicAdd(&cursor[d], 1);
        csr_src[offs[d] + pos] = s;
    }
}

// ---------------- tiled fp32 GEMM: C[M,256] = A[M,K] @ B[K,256] ----------------
// 128x64 tile, BK=16, 8x4 micro-tile per thread, 256 threads.
// Per kk: 32 FMAs vs 3 ds_read_b128 (2x better FMA:LDS ratio than 4x4).
template<int K>
__global__ __launch_bounds__(256) void gemm_kernel(const float* __restrict__ A,
                                                   const float* __restrict__ B,
                                                   float* __restrict__ C) {
    __shared__ float As[16][132];  // [kk][row 0..127], stride 528 B (16B-aligned)
    __shared__ float Bs[16][68];   // [kk][col 0..63]

    int tid = threadIdx.x;
    int tx = tid & 15;             // 16 col-groups of 4
    int ty = tid >> 4;             // 16 row-groups of 8
    int row0 = blockIdx.x * 128;
    int col0 = blockIdx.y * 64;

    float acc[8][4] = {};

    for (int k0 = 0; k0 < K; k0 += 16) {
        // A tile 128x16: 512 float4s, 2 per thread
        #pragma unroll
        for (int u = 0; u < 2; ++u) {
            int fi = tid * 2 + u;          // 0..511
            int r  = fi >> 2;              // 0..127
            int kk = (fi & 3) * 4;         // 0,4,8,12
            int row = row0 + r;
            if (row < N_NODES) {
                const float4 a4 = *(const float4*)&A[(size_t)row * K + k0 + kk];
                As[kk + 0][r] = a4.x; As[kk + 1][r] = a4.y;
                As[kk + 2][r] = a4.z; As[kk + 3][r] = a4.w;
            } else {
                As[kk + 0][r] = 0.f; As[kk + 1][r] = 0.f;
                As[kk + 2][r] = 0.f; As[kk + 3][r] = 0.f;
            }
        }
        // B tile 16x64: 256 float4s, 1 per thread
        {
            int rb = tid >> 4;             // 0..15
            int cb = (tid & 15) * 4;       // 0..60
            const float4 b4 = *(const float4*)&B[(size_t)(k0 + rb) * HIDDEN + col0 + cb];
            *(float4*)&Bs[rb][cb] = b4;
        }
        __syncthreads();

        #pragma unroll
        for (int kk = 0; kk < 16; ++kk) {
            const float4 al = *(const float4*)&As[kk][ty * 8 + 0];
            const float4 ah = *(const float4*)&As[kk][ty * 8 + 4];
            const float4 b4 = *(const float4*)&Bs[kk][tx * 4];
            float a[8] = {al.x, al.y, al.z, al.w, ah.x, ah.y, ah.z, ah.w};
            #pragma unroll
            for (int i = 0; i < 8; ++i) {
                acc[i][0] += a[i] * b4.x;
                acc[i][1] += a[i] * b4.y;
                acc[i][2] += a[i] * b4.z;
                acc[i][3] += a[i] * b4.w;
            }
        }
        __syncthreads();
    }

    #pragma unroll
    for (int i = 0; i < 8; ++i) {
        int row = row0 + ty * 8 + i;
        if (row < N_NODES) {
            float4 v = make_float4(acc[i][0], acc[i][1], acc[i][2], acc[i][3]);
            *(float4*)&C[(size_t)row * HIDDEN + col0 + tx * 4] = v;
        }
    }
}

// ---------------- input epilogue: GELU + LN on pre-activation, write h0 and cur ----------------
__global__ __launch_bounds__(256) void ln_in_kernel(const float4* __restrict__ pre,
                                                    const float4* __restrict__ b4,
                                                    const float4* __restrict__ g4,
                                                    const float4* __restrict__ beta4,
                                                    float4* __restrict__ h0,
                                                    float4* __restrict__ cur) {
    int n = blockIdx.x * 4 + (threadIdx.x >> 6);
    int lane = threadIdx.x & 63;
    if (n >= N_NODES) return;

    float4 v = pre[(size_t)n * 64 + lane];
    float4 bb = b4[lane];
    float x0 = gelu_exact(v.x + bb.x);
    float x1 = gelu_exact(v.y + bb.y);
    float x2 = gelu_exact(v.z + bb.z);
    float x3 = gelu_exact(v.w + bb.w);

    float mu = wave_sum64(x0 + x1 + x2 + x3) * (1.0f / 256.0f);
    float d0 = x0 - mu, d1 = x1 - mu, d2 = x2 - mu, d3 = x3 - mu;
    float var = wave_sum64(d0 * d0 + d1 * d1 + d2 * d2 + d3 * d3) * (1.0f / 256.0f);
    float r = rsqrtf(var + LN_EPS);

    float4 gg = g4[lane], be = beta4[lane];
    float4 out = make_float4(d0 * r * gg.x + be.x, d1 * r * gg.y + be.y,
                             d2 * r * gg.z + be.z, d3 * r * gg.w + be.w);
    h0[(size_t)n * 64 + lane]  = out;
    cur[(size_t)n * 64 + lane] = out;
}

// ---------------- gather (column-quarter, XCD-partitioned, 4-edge-groups x4 unroll) ----------------
// Grid = 10000 blocks, 4 waves/block. Dispatch index i -> quarter q=(i&7)>>1,
// node-block nb=(i>>3)*2+(i&1); under the i%8 XCD round-robin, quarter q runs on
// XCDs {2q,2q+1} so each XCD's working set is L2-resident (VERIFIED r8: FETCH 121->13.4 MB).
// Wave: 4 edge-groups x 16 lanes; each group gathers one edge's 64-col quarter slice
// as float4. Unroll 4 per group -> 16 edge-loads (4 KB) in flight per wave to cover
// the ~200cyc L2 latency of the csr->m dependent chain (r9: unroll-2 was 32 us,
// latency-exposed at 750 GB/s eff).
__global__ __launch_bounds__(256) void gather_q_kernel(const float4* __restrict__ m4,
                                                       const float* __restrict__ dinv,
                                                       const int* __restrict__ offs,
                                                       const int* __restrict__ csr_src,
                                                       const float4* __restrict__ bias4,
                                                       float4* __restrict__ pre4) {
    int i  = blockIdx.x;
    int q  = (i & 7) >> 1;
    int nb = (i >> 3) * 2 + (i & 1);
    int n  = nb * 4 + (threadIdx.x >> 6);
    int lane = threadIdx.x & 63;
    int g = lane >> 4;                 // edge-group 0..3
    int t = lane & 15;                 // float4 slot within the 64-col quarter
    int cbase = q * 16 + t;            // float4 index within the 64-float4 row

    float dn = dinv[n];

    float4 acc = make_float4(0.f, 0.f, 0.f, 0.f);
    if (g == 0) {                      // self loop, norm = 1/deg
        float4 sv = m4[(size_t)n * 64 + cbase];
        float dn2 = dn * dn;
        acc.x = sv.x * dn2; acc.y = sv.y * dn2; acc.z = sv.z * dn2; acc.w = sv.w * dn2;
    }

    int e1 = offs[n + 1];
    int ee = offs[n] + g;
    for (; ee + 12 < e1; ee += 16) {   // 4 edges per group per iteration
        int sA = csr_src[ee];
        int sB = csr_src[ee + 4];
        int sC = csr_src[ee + 8];
        int sD = csr_src[ee + 12];
        float4 vA = m4[(size_t)sA * 64 + cbase];
        float4 vB = m4[(size_t)sB * 64 + cbase];
        float4 vC = m4[(size_t)sC * 64 + cbase];
        float4 vD = m4[(size_t)sD * 64 + cbase];
        float wA = dinv[sA] * dn;
        float wB = dinv[sB] * dn;
        float wC = dinv[sC] * dn;
        float wD = dinv[sD] * dn;
        acc.x += wA * vA.x + wB * vB.x + wC * vC.x + wD * vD.x;
        acc.y += wA * vA.y + wB * vB.y + wC * vC.y + wD * vD.y;
        acc.z += wA * vA.z + wB * vB.z + wC * vC.z + wD * vD.z;
        acc.w += wA * vA.w + wB * vB.w + wC * vC.w + wD * vD.w;
    }
    for (; ee < e1; ee += 4) {
        int s = csr_src[ee];
        float4 v = m4[(size_t)s * 64 + cbase];
        float w = dinv[s] * dn;
        acc.x += w * v.x; acc.y += w * v.y; acc.z += w * v.z; acc.w += w * v.w;
    }

    // combine the 4 edge-groups (lanes that share t)
    acc.x += __shfl_xor(acc.x, 16);
    acc.y += __shfl_xor(acc.y, 16);
    acc.z += __shfl_xor(acc.z, 16);
    acc.w += __shfl_xor(acc.w, 16);
    acc.x += __shfl_xor(acc.x, 32);
    acc.y += __shfl_xor(acc.y, 32);
    acc.z += __shfl_xor(acc.z, 32);
    acc.w += __shfl_xor(acc.w, 32);

    if (g == 0) {
        float4 bb = bias4[cbase];
        pre4[(size_t)n * 64 + cbase] = make_float4(acc.x + bb.x, acc.y + bb.y,
                                                   acc.z + bb.z, acc.w + bb.w);
    }
}

// ---------------- GELU + LN + residual (reads pre, updates cur in place) ----------------
// one WAVE per node (4 nodes/block); lane owns 4 columns; LN via wave shuffles.
__global__ __launch_bounds__(256) void ln_res_kernel(const float4* __restrict__ pre4,
                                                     const float4* __restrict__ g4,
                                                     const float4* __restrict__ beta4,
                                                     const float4* __restrict__ h04,
                                                     float4* __restrict__ cur4) {
    int n = blockIdx.x * 4 + (threadIdx.x >> 6);
    int lane = threadIdx.x & 63;
    if (n >= N_NODES) return;

    float4 v = pre4[(size_t)n * 64 + lane];   // bias already included
    float x0 = gelu_exact(v.x);
    float x1 = gelu_exact(v.y);
    float x2 = gelu_exact(v.z);
    float x3 = gelu_exact(v.w);

    float mu = wave_sum64(x0 + x1 + x2 + x3) * (1.0f / 256.0f);
    float d0 = x0 - mu, d1 = x1 - mu, d2 = x2 - mu, d3 = x3 - mu;
    float var = wave_sum64(d0 * d0 + d1 * d1 + d2 * d2 + d3 * d3) * (1.0f / 256.0f);
    float r = rsqrtf(var + LN_EPS);

    float4 gg = g4[lane], be = beta4[lane];
    float h0v = d0 * r * gg.x + be.x;
    float h1v = d1 * r * gg.y + be.y;
    float h2v = d2 * r * gg.z + be.z;
    float h3v = d3 * r * gg.w + be.w;

    size_t idx = (size_t)n * 64 + lane;
    float4 c = cur4[idx];
    float4 h = h04[idx];
    float4 o = make_float4(c.x + (1.0f - ALPHA) * h0v + ALPHA * h.x,
                           c.y + (1.0f - ALPHA) * h1v + ALPHA * h.y,
                           c.z + (1.0f - ALPHA) * h2v + ALPHA * h.z,
                           c.w + (1.0f - ALPHA) * h3v + ALPHA * h.w);
    cur4[idx] = o;
}

// ---------------- launcher ----------------

extern "C" void kernel_launch(void* const* d_in, const int* in_sizes, int n_in,
                              void* d_out, int out_size, void* d_ws, size_t ws_size,
                              hipStream_t stream) {
    const float* x      = (const float*)d_in[0];
    const int*   ei     = (const int*)  d_in[1];   // (2, E): [0]=src, [1]=dst
    const float* W_in   = (const float*)d_in[2];
    const float* b_in   = (const float*)d_in[3];
    const float* g_in   = (const float*)d_in[4];
    const float* bt_in  = (const float*)d_in[5];
    const float* Wl     = (const float*)d_in[6];   // (L, 256, 256)
    const float* bl     = (const float*)d_in[7];
    const float* gl     = (const float*)d_in[8];
    const float* betal  = (const float*)d_in[9];

    const int* src = ei;
    const int* dst = ei + N_EDGES;

    float* cur = (float*)d_out;

    char* w = (char*)d_ws;
    size_t off = 0;
    auto alloc = [&](size_t bytes) -> void* {
        void* p = w + off;
        off = (off + bytes + 255) & ~(size_t)255;
        return p;
    };
    int*   cnt      = (int*)  alloc(N_NODES * sizeof(int));
    int*   cursor   = (int*)  alloc(N_NODES * sizeof(int));
    int*   offs     = (int*)  alloc((N_NODES + 1) * sizeof(int));
    float* dinv     = (float*)alloc(N_NODES * sizeof(float));
    int*   csr_src  = (int*)  alloc(N_EDGES * sizeof(int));
    float* h0       = (float*)alloc((size_t)N_NODES * HIDDEN * sizeof(float));
    float* m        = (float*)alloc((size_t)N_NODES * HIDDEN * sizeof(float));
    float* pre      = (float*)alloc((size_t)N_NODES * HIDDEN * sizeof(float));

    hipMemsetAsync(cnt,    0, N_NODES * sizeof(int), stream);
    hipMemsetAsync(cursor, 0, N_NODES * sizeof(int), stream);

    const int EB = (N_EDGES + 255) / 256;
    const int NB = (N_NODES + 255) / 256;
    const int NODE_BLOCKS = (N_NODES + 3) / 4;   // 2500: 1 wave per node, 4 nodes/block

    count_deg_kernel<<<EB, 256, 0, stream>>>(dst, cnt);
    dinv_kernel<<<NB, 256, 0, stream>>>(cnt, dinv);
    scan_kernel<<<1, 256, 0, stream>>>(cnt, offs);
    fill_csr_kernel<<<EB, 256, 0, stream>>>(src, dst, offs, cursor, csr_src);

    dim3 ggrid((N_NODES + 127) / 128, HIDDEN / 64);   // 79 x 4

    // input block: GEMM (K=128) -> fused GELU+LN writing h0 and cur
    gemm_kernel<IN_DIM><<<ggrid, 256, 0, stream>>>(x, W_in, m);
    ln_in_kernel<<<NODE_BLOCKS, 256, 0, stream>>>((const float4*)m, (const float4*)b_in,
                                                  (const float4*)g_in, (const float4*)bt_in,
                                                  (float4*)h0, (float4*)cur);

    for (int l = 0; l < NUM_LAYERS; ++l) {
        gemm_kernel<HIDDEN><<<ggrid, 256, 0, stream>>>(cur, Wl + (size_t)l * HIDDEN * HIDDEN, m);
        gather_q_kernel<<<NODE_BLOCKS * 4, 256, 0, stream>>>((const float4*)m, dinv, offs, csr_src,
                                                             (const float4*)(bl + l * HIDDEN),
                                                             (float4*)pre);
        ln_res_kernel<<<NODE_BLOCKS, 256, 0, stream>>>((const float4*)pre,
                                                       (const float4*)(gl + l * HIDDEN),
                                                       (const float4*)(betal + l * HIDDEN),
                                                       (const float4*)h0, (float4*)cur);
    }
}

// Round 12
// 517.011 us; speedup vs baseline: 1.0677x; 1.0677x over previous
//
#include <hip/hip_runtime.h>
#include <math.h>

#define N_NODES   10000
#define N_EDGES   320000
#define IN_DIM    128
#define HIDDEN    256
#define NUM_LAYERS 6
#define ALPHA     0.1f
#define LN_EPS    1e-5f

__device__ __forceinline__ float gelu_exact(float x) {
    // jax.nn.gelu(approximate=False): 0.5*x*(1+erf(x/sqrt(2)))
    return 0.5f * x * (1.0f + erff(x * 0.70710678118654752440f));
}

__device__ __forceinline__ float wave_sum64(float v) {
#pragma unroll
    for (int i = 32; i > 0; i >>= 1) v += __shfl_xor(v, i);
    return v;
}

// ---------------- graph preprocessing ----------------

__global__ __launch_bounds__(256) void count_deg_kernel(const int* __restrict__ dst,
                                                        int* __restrict__ cnt) {
    int e = blockIdx.x * 256 + threadIdx.x;
    if (e < N_EDGES) atomicAdd(&cnt[dst[e]], 1);
}

__global__ __launch_bounds__(256) void dinv_kernel(const int* __restrict__ cnt,
                                                   float* __restrict__ dinv) {
    int i = blockIdx.x * 256 + threadIdx.x;
    // +1 for the self loop; deg >= 1 always so the deg>0 guard is moot
    if (i < N_NODES) dinv[i] = rsqrtf((float)(cnt[i] + 1));
}

// single-block exclusive scan over 10000 counts -> CSR row offsets
__global__ __launch_bounds__(256) void scan_kernel(const int* __restrict__ cnt,
                                                   int* __restrict__ offs) {
    __shared__ int sums[256];
    __shared__ int bases[257];
    int t = threadIdx.x;
    const int chunk = (N_NODES + 255) / 256;  // 40
    int b0 = t * chunk;
    int b1 = b0 + chunk; if (b1 > N_NODES) b1 = N_NODES;
    if (b0 > N_NODES) b0 = N_NODES;
    int s = 0;
    for (int i = b0; i < b1; ++i) s += cnt[i];
    sums[t] = s;
    __syncthreads();
    if (t == 0) {
        int r = 0;
        for (int i = 0; i < 256; ++i) { bases[i] = r; r += sums[i]; }
        bases[256] = r;
    }
    __syncthreads();
    int r = bases[t];
    for (int i = b0; i < b1; ++i) { offs[i] = r; r += cnt[i]; }
    if (t == 0) offs[N_NODES] = bases[256];
}

__global__ __launch_bounds__(256) void fill_csr_kernel(const int* __restrict__ src,
                                                       const int* __restrict__ dst,
                                                       const int* __restrict__ offs,
                                                       int* __restrict__ cursor,
                                                       int* __restrict__ csr_src) {
    int e = blockIdx.x * 256 + threadIdx.x;
    if (e < N_EDGES) {
        int d = dst[e], s = src[e];
        int pos = atomicAdd(&cursor[d], 1);
        csr_src[offs[d] + pos] = s;
    }
}

// ---------------- tiled fp32 GEMM: C[M,256] = A[M,K] @ B[K,256] ----------------
// 64x64 tile, BK=16, 4x4 micro-tile per thread, 256 threads.
// REVERTED from 128x64/8x4 (r11): that config had 316 blocks = 1.23 waves/SIMD,
// too few to hide ds_read latency (occupancy-starved, +26us). 64x64 gives 628
// blocks = 2.45 waves/SIMD (measured-good in r3-r8).
template<int K>
__global__ __launch_bounds__(256) void gemm_kernel(const float* __restrict__ A,
                                                   const float* __restrict__ B,
                                                   float* __restrict__ C) {
    __shared__ float As[16][68];  // [kk][row], 16B-aligned rows
    __shared__ float Bs[16][68];  // [kk][col]

    int tid = threadIdx.x;
    int tx = tid & 15;
    int ty = tid >> 4;
    int row0 = blockIdx.x * 64;
    int col0 = blockIdx.y * 64;

    float acc[4][4] = {};

    for (int k0 = 0; k0 < K; k0 += 16) {
        {
            int idx = tid * 4;
            int r  = idx >> 4;     // 0..63
            int kk = idx & 15;     // 0,4,8,12
            int row = row0 + r;
            if (row < N_NODES) {
                const float4 a4 = *(const float4*)&A[(size_t)row * K + k0 + kk];
                As[kk + 0][r] = a4.x; As[kk + 1][r] = a4.y;
                As[kk + 2][r] = a4.z; As[kk + 3][r] = a4.w;
            } else {
                As[kk + 0][r] = 0.f; As[kk + 1][r] = 0.f;
                As[kk + 2][r] = 0.f; As[kk + 3][r] = 0.f;
            }
        }
        {
            int idx = tid * 4;
            int rb = idx >> 6;     // 0..15
            int cb = idx & 63;     // multiple of 4
            const float4 b4 = *(const float4*)&B[(size_t)(k0 + rb) * HIDDEN + col0 + cb];
            *(float4*)&Bs[rb][cb] = b4;
        }
        __syncthreads();

        #pragma unroll
        for (int kk = 0; kk < 16; ++kk) {
            const float4 a4 = *(const float4*)&As[kk][ty * 4];
            const float4 b4 = *(const float4*)&Bs[kk][tx * 4];
            acc[0][0] += a4.x * b4.x; acc[0][1] += a4.x * b4.y; acc[0][2] += a4.x * b4.z; acc[0][3] += a4.x * b4.w;
            acc[1][0] += a4.y * b4.x; acc[1][1] += a4.y * b4.y; acc[1][2] += a4.y * b4.z; acc[1][3] += a4.y * b4.w;
            acc[2][0] += a4.z * b4.x; acc[2][1] += a4.z * b4.y; acc[2][2] += a4.z * b4.z; acc[2][3] += a4.z * b4.w;
            acc[3][0] += a4.w * b4.x; acc[3][1] += a4.w * b4.y; acc[3][2] += a4.w * b4.z; acc[3][3] += a4.w * b4.w;
        }
        __syncthreads();
    }

    #pragma unroll
    for (int i = 0; i < 4; ++i) {
        int row = row0 + ty * 4 + i;
        if (row < N_NODES) {
            float4 v = make_float4(acc[i][0], acc[i][1], acc[i][2], acc[i][3]);
            *(float4*)&C[(size_t)row * HIDDEN + col0 + tx * 4] = v;
        }
    }
}

// ---------------- input epilogue: GELU + LN on pre-activation, write h0 and cur ----------------
__global__ __launch_bounds__(256) void ln_in_kernel(const float4* __restrict__ pre,
                                                    const float4* __restrict__ b4,
                                                    const float4* __restrict__ g4,
                                                    const float4* __restrict__ beta4,
                                                    float4* __restrict__ h0,
                                                    float4* __restrict__ cur) {
    int n = blockIdx.x * 4 + (threadIdx.x >> 6);
    int lane = threadIdx.x & 63;
    if (n >= N_NODES) return;

    float4 v = pre[(size_t)n * 64 + lane];
    float4 bb = b4[lane];
    float x0 = gelu_exact(v.x + bb.x);
    float x1 = gelu_exact(v.y + bb.y);
    float x2 = gelu_exact(v.z + bb.z);
    float x3 = gelu_exact(v.w + bb.w);

    float mu = wave_sum64(x0 + x1 + x2 + x3) * (1.0f / 256.0f);
    float d0 = x0 - mu, d1 = x1 - mu, d2 = x2 - mu, d3 = x3 - mu;
    float var = wave_sum64(d0 * d0 + d1 * d1 + d2 * d2 + d3 * d3) * (1.0f / 256.0f);
    float r = rsqrtf(var + LN_EPS);

    float4 gg = g4[lane], be = beta4[lane];
    float4 out = make_float4(d0 * r * gg.x + be.x, d1 * r * gg.y + be.y,
                             d2 * r * gg.z + be.z, d3 * r * gg.w + be.w);
    h0[(size_t)n * 64 + lane]  = out;
    cur[(size_t)n * 64 + lane] = out;
}

// ---------------- gather (column-quarter, XCD-partitioned, 4-edge-groups x4 unroll) ----------------
// Grid = 10000 blocks, 4 waves/block. Dispatch index i -> quarter q=(i&7)>>1,
// node-block nb=(i>>3)*2+(i&1); under the i%8 XCD round-robin, quarter q runs on
// XCDs {2q,2q+1} so each XCD's working set is L2-resident (VERIFIED r8: FETCH 121->13.4 MB).
// Wave: 4 edge-groups x 16 lanes; each group gathers one edge's 64-col quarter slice
// as float4. Unroll 4 per group -> 16 edge-loads (4 KB) in flight per wave.
__global__ __launch_bounds__(256) void gather_q_kernel(const float4* __restrict__ m4,
                                                       const float* __restrict__ dinv,
                                                       const int* __restrict__ offs,
                                                       const int* __restrict__ csr_src,
                                                       const float4* __restrict__ bias4,
                                                       float4* __restrict__ pre4) {
    int i  = blockIdx.x;
    int q  = (i & 7) >> 1;
    int nb = (i >> 3) * 2 + (i & 1);
    int n  = nb * 4 + (threadIdx.x >> 6);
    int lane = threadIdx.x & 63;
    int g = lane >> 4;                 // edge-group 0..3
    int t = lane & 15;                 // float4 slot within the 64-col quarter
    int cbase = q * 16 + t;            // float4 index within the 64-float4 row

    float dn = dinv[n];

    float4 acc = make_float4(0.f, 0.f, 0.f, 0.f);
    if (g == 0) {                      // self loop, norm = 1/deg
        float4 sv = m4[(size_t)n * 64 + cbase];
        float dn2 = dn * dn;
        acc.x = sv.x * dn2; acc.y = sv.y * dn2; acc.z = sv.z * dn2; acc.w = sv.w * dn2;
    }

    int e1 = offs[n + 1];
    int ee = offs[n] + g;
    for (; ee + 12 < e1; ee += 16) {   // 4 edges per group per iteration
        int sA = csr_src[ee];
        int sB = csr_src[ee + 4];
        int sC = csr_src[ee + 8];
        int sD = csr_src[ee + 12];
        float4 vA = m4[(size_t)sA * 64 + cbase];
        float4 vB = m4[(size_t)sB * 64 + cbase];
        float4 vC = m4[(size_t)sC * 64 + cbase];
        float4 vD = m4[(size_t)sD * 64 + cbase];
        float wA = dinv[sA] * dn;
        float wB = dinv[sB] * dn;
        float wC = dinv[sC] * dn;
        float wD = dinv[sD] * dn;
        acc.x += wA * vA.x + wB * vB.x + wC * vC.x + wD * vD.x;
        acc.y += wA * vA.y + wB * vB.y + wC * vC.y + wD * vD.y;
        acc.z += wA * vA.z + wB * vB.z + wC * vC.z + wD * vD.z;
        acc.w += wA * vA.w + wB * vB.w + wC * vC.w + wD * vD.w;
    }
    for (; ee < e1; ee += 4) {
        int s = csr_src[ee];
        float4 v = m4[(size_t)s * 64 + cbase];
        float w = dinv[s] * dn;
        acc.x += w * v.x; acc.y += w * v.y; acc.z += w * v.z; acc.w += w * v.w;
    }

    // combine the 4 edge-groups (lanes that share t)
    acc.x += __shfl_xor(acc.x, 16);
    acc.y += __shfl_xor(acc.y, 16);
    acc.z += __shfl_xor(acc.z, 16);
    acc.w += __shfl_xor(acc.w, 16);
    acc.x += __shfl_xor(acc.x, 32);
    acc.y += __shfl_xor(acc.y, 32);
    acc.z += __shfl_xor(acc.z, 32);
    acc.w += __shfl_xor(acc.w, 32);

    if (g == 0) {
        float4 bb = bias4[cbase];
        pre4[(size_t)n * 64 + cbase] = make_float4(acc.x + bb.x, acc.y + bb.y,
                                                   acc.z + bb.z, acc.w + bb.w);
    }
}

// ---------------- GELU + LN + residual (reads pre, updates cur in place) ----------------
// one WAVE per node (4 nodes/block); lane owns 4 columns; LN via wave shuffles.
__global__ __launch_bounds__(256) void ln_res_kernel(const float4* __restrict__ pre4,
                                                     const float4* __restrict__ g4,
                                                     const float4* __restrict__ beta4,
                                                     const float4* __restrict__ h04,
                                                     float4* __restrict__ cur4) {
    int n = blockIdx.x * 4 + (threadIdx.x >> 6);
    int lane = threadIdx.x & 63;
    if (n >= N_NODES) return;

    float4 v = pre4[(size_t)n * 64 + lane];   // bias already included
    float x0 = gelu_exact(v.x);
    float x1 = gelu_exact(v.y);
    float x2 = gelu_exact(v.z);
    float x3 = gelu_exact(v.w);

    float mu = wave_sum64(x0 + x1 + x2 + x3) * (1.0f / 256.0f);
    float d0 = x0 - mu, d1 = x1 - mu, d2 = x2 - mu, d3 = x3 - mu;
    float var = wave_sum64(d0 * d0 + d1 * d1 + d2 * d2 + d3 * d3) * (1.0f / 256.0f);
    float r = rsqrtf(var + LN_EPS);

    float4 gg = g4[lane], be = beta4[lane];
    float h0v = d0 * r * gg.x + be.x;
    float h1v = d1 * r * gg.y + be.y;
    float h2v = d2 * r * gg.z + be.z;
    float h3v = d3 * r * gg.w + be.w;

    size_t idx = (size_t)n * 64 + lane;
    float4 c = cur4[idx];
    float4 h = h04[idx];
    float4 o = make_float4(c.x + (1.0f - ALPHA) * h0v + ALPHA * h.x,
                           c.y + (1.0f - ALPHA) * h1v + ALPHA * h.y,
                           c.z + (1.0f - ALPHA) * h2v + ALPHA * h.z,
                           c.w + (1.0f - ALPHA) * h3v + ALPHA * h.w);
    cur4[idx] = o;
}

// ---------------- launcher ----------------

extern "C" void kernel_launch(void* const* d_in, const int* in_sizes, int n_in,
                              void* d_out, int out_size, void* d_ws, size_t ws_size,
                              hipStream_t stream) {
    const float* x      = (const float*)d_in[0];
    const int*   ei     = (const int*)  d_in[1];   // (2, E): [0]=src, [1]=dst
    const float* W_in   = (const float*)d_in[2];
    const float* b_in   = (const float*)d_in[3];
    const float* g_in   = (const float*)d_in[4];
    const float* bt_in  = (const float*)d_in[5];
    const float* Wl     = (const float*)d_in[6];   // (L, 256, 256)
    const float* bl     = (const float*)d_in[7];
    const float* gl     = (const float*)d_in[8];
    const float* betal  = (const float*)d_in[9];

    const int* src = ei;
    const int* dst = ei + N_EDGES;

    float* cur = (float*)d_out;

    char* w = (char*)d_ws;
    size_t off = 0;
    auto alloc = [&](size_t bytes) -> void* {
        void* p = w + off;
        off = (off + bytes + 255) & ~(size_t)255;
        return p;
    };
    int*   cnt      = (int*)  alloc(N_NODES * sizeof(int));
    int*   cursor   = (int*)  alloc(N_NODES * sizeof(int));
    int*   offs     = (int*)  alloc((N_NODES + 1) * sizeof(int));
    float* dinv     = (float*)alloc(N_NODES * sizeof(float));
    int*   csr_src  = (int*)  alloc(N_EDGES * sizeof(int));
    float* h0       = (float*)alloc((size_t)N_NODES * HIDDEN * sizeof(float));
    float* m        = (float*)alloc((size_t)N_NODES * HIDDEN * sizeof(float));
    float* pre      = (float*)alloc((size_t)N_NODES * HIDDEN * sizeof(float));

    hipMemsetAsync(cnt,    0, N_NODES * sizeof(int), stream);
    hipMemsetAsync(cursor, 0, N_NODES * sizeof(int), stream);

    const int EB = (N_EDGES + 255) / 256;
    const int NB = (N_NODES + 255) / 256;
    const int NODE_BLOCKS = (N_NODES + 3) / 4;   // 2500: 1 wave per node, 4 nodes/block

    count_deg_kernel<<<EB, 256, 0, stream>>>(dst, cnt);
    dinv_kernel<<<NB, 256, 0, stream>>>(cnt, dinv);
    scan_kernel<<<1, 256, 0, stream>>>(cnt, offs);
    fill_csr_kernel<<<EB, 256, 0, stream>>>(src, dst, offs, cursor, csr_src);

    dim3 ggrid((N_NODES + 63) / 64, HIDDEN / 64);   // 157 x 4 = 628 blocks

    // input block: GEMM (K=128) -> fused GELU+LN writing h0 and cur
    gemm_kernel<IN_DIM><<<ggrid, 256, 0, stream>>>(x, W_in, m);
    ln_in_kernel<<<NODE_BLOCKS, 256, 0, stream>>>((const float4*)m, (const float4*)b_in,
                                                  (const float4*)g_in, (const float4*)bt_in,
                                                  (float4*)h0, (float4*)cur);

    for (int l = 0; l < NUM_LAYERS; ++l) {
        gemm_kernel<HIDDEN><<<ggrid, 256, 0, stream>>>(cur, Wl + (size_t)l * HIDDEN * HIDDEN, m);
        gather_q_kernel<<<NODE_BLOCKS * 4, 256, 0, stream>>>((const float4*)m, dinv, offs, csr_src,
                                                             (const float4*)(bl + l * HIDDEN),
                                                             (float4*)pre);
        ln_res_kernel<<<NODE_BLOCKS, 256, 0, stream>>>((const float4*)pre,
                                                       (const float4*)(gl + l * HIDDEN),
                                                       (const float4*)(betal + l * HIDDEN),
                                                       (const float4*)h0, (float4*)cur);
    }
}

// Round 14
// 451.503 us; speedup vs baseline: 1.2226x; 1.1451x over previous
//
#include <hip/hip_runtime.h>
#include <math.h>

#define N_NODES   10000
#define N_EDGES   320000
#define IN_DIM    128
#define HIDDEN    256
#define NUM_LAYERS 6
#define ALPHA     0.1f
#define LN_EPS    1e-5f

using bf16x8 = __attribute__((ext_vector_type(8))) __bf16;
using f32x4  = __attribute__((ext_vector_type(4))) float;

__device__ __forceinline__ float gelu_exact(float x) {
    // jax.nn.gelu(approximate=False): 0.5*x*(1+erf(x/sqrt(2)))
    return 0.5f * x * (1.0f + erff(x * 0.70710678118654752440f));
}

__device__ __forceinline__ float wave_sum64(float v) {
#pragma unroll
    for (int i = 32; i > 0; i >>= 1) v += __shfl_xor(v, i);
    return v;
}

// fp32 -> bf16 round-to-nearest-even, and back
__device__ __forceinline__ unsigned short f2bf(float f) {
    unsigned u = __float_as_uint(f);
    return (unsigned short)((u + 0x7FFF + ((u >> 16) & 1)) >> 16);
}
__device__ __forceinline__ float bf2f(unsigned short h) {
    return __uint_as_float(((unsigned)h) << 16);
}

// ---------------- graph preprocessing ----------------

__global__ __launch_bounds__(256) void count_deg_kernel(const int* __restrict__ dst,
                                                        int* __restrict__ cnt) {
    int e = blockIdx.x * 256 + threadIdx.x;
    if (e < N_EDGES) atomicAdd(&cnt[dst[e]], 1);
}

__global__ __launch_bounds__(256) void dinv_kernel(const int* __restrict__ cnt,
                                                   float* __restrict__ dinv) {
    int i = blockIdx.x * 256 + threadIdx.x;
    if (i < N_NODES) dinv[i] = rsqrtf((float)(cnt[i] + 1));  // +1 self loop
}

__global__ __launch_bounds__(256) void scan_kernel(const int* __restrict__ cnt,
                                                   int* __restrict__ offs) {
    __shared__ int sums[256];
    __shared__ int bases[257];
    int t = threadIdx.x;
    const int chunk = (N_NODES + 255) / 256;  // 40
    int b0 = t * chunk;
    int b1 = b0 + chunk; if (b1 > N_NODES) b1 = N_NODES;
    if (b0 > N_NODES) b0 = N_NODES;
    int s = 0;
    for (int i = b0; i < b1; ++i) s += cnt[i];
    sums[t] = s;
    __syncthreads();
    if (t == 0) {
        int r = 0;
        for (int i = 0; i < 256; ++i) { bases[i] = r; r += sums[i]; }
        bases[256] = r;
    }
    __syncthreads();
    int r = bases[t];
    for (int i = b0; i < b1; ++i) { offs[i] = r; r += cnt[i]; }
    if (t == 0) offs[N_NODES] = bases[256];
}

__global__ __launch_bounds__(256) void fill_csr_kernel(const int* __restrict__ src,
                                                       const int* __restrict__ dst,
                                                       const int* __restrict__ offs,
                                                       int* __restrict__ cursor,
                                                       int* __restrict__ csr_src) {
    int e = blockIdx.x * 256 + threadIdx.x;
    if (e < N_EDGES) {
        int d = dst[e], s = src[e];
        int pos = atomicAdd(&cursor[d], 1);
        csr_src[offs[d] + pos] = s;
    }
}

// ---------------- weight prep: transpose + hi/lo bf16 split ----------------
// W [K][256] row-major -> Wt_hi/Wt_lo [256][K] bf16 (K-contiguous rows for MFMA frags).
// grid (8,8,7): z<6 -> Wl layer z (K=256); z==6 -> W_in (K=128, base 6*65536).
__global__ __launch_bounds__(256) void prep_w_kernel(const float* __restrict__ Wl,
                                                     const float* __restrict__ W_in,
                                                     unsigned short* __restrict__ hi,
                                                     unsigned short* __restrict__ lo) {
    int z = blockIdx.z;
    const float* W;
    unsigned short *ho, *lg;
    int K;
    if (z < 6) {
        W = Wl + (size_t)z * HIDDEN * HIDDEN; K = HIDDEN;
        ho = hi + (size_t)z * HIDDEN * HIDDEN;
        lg = lo + (size_t)z * HIDDEN * HIDDEN;
    } else {
        W = W_in; K = IN_DIM;
        ho = hi + (size_t)6 * HIDDEN * HIDDEN;
        lg = lo + (size_t)6 * HIDDEN * HIDDEN;
    }
    int tk0 = blockIdx.x * 32;
    if (tk0 >= K) return;
    int tn0 = blockIdx.y * 32;

    __shared__ float T[32][33];
    int tx = threadIdx.x & 31, ty = threadIdx.x >> 5;   // 32 x 8
    #pragma unroll
    for (int i = 0; i < 32; i += 8)
        T[ty + i][tx] = W[(size_t)(tk0 + ty + i) * HIDDEN + tn0 + tx];
    __syncthreads();
    #pragma unroll
    for (int i = 0; i < 32; i += 8) {
        int n = tn0 + ty + i, k = tk0 + tx;
        float v = T[tx][ty + i];
        unsigned short h = f2bf(v);
        ho[(size_t)n * K + k] = h;
        lg[(size_t)n * K + k] = f2bf(v - bf2f(h));
    }
}

// ---------------- MFMA GEMM: C[M,256] = A[M,K] @ B[K,256], split-bf16 (~fp32 acc) ----------------
// m97-family structure (guide-verified): 64x64 tile, 4 waves 2x2, both A and B staged per
// 32-K step as bf16 hi/lo. Frags: lane l reads 8 CONTIGUOUS bf16 (ds_read_b128) at
// row/col (l&15), k-offset (l>>4)*8 -- identical slot->k map for A and B (permutation-safe).
// C/D (m89-verified): col=lane&15, row=(lane>>4)*4+reg. 3 MFMAs/frag-pair: hh+lh+hl.
// LDS 4 x [64][40] u16 = 20 KB -> ~6 blocks/CU (r12 lesson: occupancy is the lever).
template<int K>
__global__ __launch_bounds__(256) void gemm_mfma_kernel(const float* __restrict__ A,
                                                        const unsigned short* __restrict__ Bh,
                                                        const unsigned short* __restrict__ Bl,
                                                        float* __restrict__ C) {
    __shared__ unsigned short AsH[64][40];
    __shared__ unsigned short AsL[64][40];
    __shared__ unsigned short BsH[64][40];
    __shared__ unsigned short BsL[64][40];

    int tid  = threadIdx.x;
    int row0 = blockIdx.x * 64;
    int col0 = blockIdx.y * 64;

    int l  = tid & 63, w = tid >> 6;
    int wr = w >> 1, wc = w & 1;
    int r  = l & 15, kb = l >> 4;

    f32x4 acc00 = {0.f, 0.f, 0.f, 0.f};
    f32x4 acc01 = acc00, acc10 = acc00, acc11 = acc00;

    for (int k0 = 0; k0 < K; k0 += 32) {
        __syncthreads();   // prior iteration's frag reads done before restaging
        // stage A 64x32 fp32 -> bf16 hi/lo
        #pragma unroll
        for (int u = 0; u < 2; ++u) {
            int fi = tid * 2 + u;          // 0..511
            int row = fi >> 3, f4 = fi & 7;
            float4 a = make_float4(0.f, 0.f, 0.f, 0.f);
            if (row0 + row < N_NODES)
                a = *(const float4*)&A[(size_t)(row0 + row) * K + k0 + f4 * 4];
            unsigned short h0 = f2bf(a.x), h1 = f2bf(a.y), h2 = f2bf(a.z), h3 = f2bf(a.w);
            *(short4*)&AsH[row][f4 * 4] = make_short4((short)h0, (short)h1, (short)h2, (short)h3);
            *(short4*)&AsL[row][f4 * 4] = make_short4((short)f2bf(a.x - bf2f(h0)),
                                                      (short)f2bf(a.y - bf2f(h1)),
                                                      (short)f2bf(a.z - bf2f(h2)),
                                                      (short)f2bf(a.w - bf2f(h3)));
        }
        // stage B strip 64x32 bf16 hi/lo (Wt is [256][K] K-contiguous)
        #pragma unroll
        for (int u = 0; u < 2; ++u) {
            int fi = tid * 2 + u;          // 0..511
            int row = fi >> 3, sg = fi & 7;
            *(short4*)&BsH[row][sg * 4] = *(const short4*)&Bh[(size_t)(col0 + row) * K + k0 + sg * 4];
            *(short4*)&BsL[row][sg * 4] = *(const short4*)&Bl[(size_t)(col0 + row) * K + k0 + sg * 4];
        }
        __syncthreads();

        bf16x8 ah0 = *(const bf16x8*)&AsH[wr * 32 +  0 + r][kb * 8];
        bf16x8 ah1 = *(const bf16x8*)&AsH[wr * 32 + 16 + r][kb * 8];
        bf16x8 al0 = *(const bf16x8*)&AsL[wr * 32 +  0 + r][kb * 8];
        bf16x8 al1 = *(const bf16x8*)&AsL[wr * 32 + 16 + r][kb * 8];
        bf16x8 bh0 = *(const bf16x8*)&BsH[wc * 32 +  0 + r][kb * 8];
        bf16x8 bh1 = *(const bf16x8*)&BsH[wc * 32 + 16 + r][kb * 8];
        bf16x8 bl0 = *(const bf16x8*)&BsL[wc * 32 +  0 + r][kb * 8];
        bf16x8 bl1 = *(const bf16x8*)&BsL[wc * 32 + 16 + r][kb * 8];

        acc00 = __builtin_amdgcn_mfma_f32_16x16x32_bf16(ah0, bh0, acc00, 0, 0, 0);
        acc01 = __builtin_amdgcn_mfma_f32_16x16x32_bf16(ah0, bh1, acc01, 0, 0, 0);
        acc10 = __builtin_amdgcn_mfma_f32_16x16x32_bf16(ah1, bh0, acc10, 0, 0, 0);
        acc11 = __builtin_amdgcn_mfma_f32_16x16x32_bf16(ah1, bh1, acc11, 0, 0, 0);
        acc00 = __builtin_amdgcn_mfma_f32_16x16x32_bf16(al0, bh0, acc00, 0, 0, 0);
        acc01 = __builtin_amdgcn_mfma_f32_16x16x32_bf16(al0, bh1, acc01, 0, 0, 0);
        acc10 = __builtin_amdgcn_mfma_f32_16x16x32_bf16(al1, bh0, acc10, 0, 0, 0);
        acc11 = __builtin_amdgcn_mfma_f32_16x16x32_bf16(al1, bh1, acc11, 0, 0, 0);
        acc00 = __builtin_amdgcn_mfma_f32_16x16x32_bf16(ah0, bl0, acc00, 0, 0, 0);
        acc01 = __builtin_amdgcn_mfma_f32_16x16x32_bf16(ah0, bl1, acc01, 0, 0, 0);
        acc10 = __builtin_amdgcn_mfma_f32_16x16x32_bf16(ah1, bl0, acc10, 0, 0, 0);
        acc11 = __builtin_amdgcn_mfma_f32_16x16x32_bf16(ah1, bl1, acc11, 0, 0, 0);
    }

    #define WRITE_ACC(accv, i, j)                                              \
    {                                                                          \
        int gcol = col0 + wc * 32 + (j) * 16 + r;                              \
        _Pragma("unroll")                                                      \
        for (int reg = 0; reg < 4; ++reg) {                                    \
            int grow = row0 + wr * 32 + (i) * 16 + kb * 4 + reg;               \
            if (grow < N_NODES) C[(size_t)grow * HIDDEN + gcol] = accv[reg];   \
        }                                                                      \
    }
    WRITE_ACC(acc00, 0, 0); WRITE_ACC(acc01, 0, 1);
    WRITE_ACC(acc10, 1, 0); WRITE_ACC(acc11, 1, 1);
    #undef WRITE_ACC
}

// ---------------- input epilogue: GELU + LN on pre-activation, write h0 and cur ----------------
__global__ __launch_bounds__(256) void ln_in_kernel(const float4* __restrict__ pre,
                                                    const float4* __restrict__ b4,
                                                    const float4* __restrict__ g4,
                                                    const float4* __restrict__ beta4,
                                                    float4* __restrict__ h0,
                                                    float4* __restrict__ cur) {
    int n = blockIdx.x * 4 + (threadIdx.x >> 6);
    int lane = threadIdx.x & 63;
    if (n >= N_NODES) return;

    float4 v = pre[(size_t)n * 64 + lane];
    float4 bb = b4[lane];
    float x0 = gelu_exact(v.x + bb.x);
    float x1 = gelu_exact(v.y + bb.y);
    float x2 = gelu_exact(v.z + bb.z);
    float x3 = gelu_exact(v.w + bb.w);

    float mu = wave_sum64(x0 + x1 + x2 + x3) * (1.0f / 256.0f);
    float d0 = x0 - mu, d1 = x1 - mu, d2 = x2 - mu, d3 = x3 - mu;
    float var = wave_sum64(d0 * d0 + d1 * d1 + d2 * d2 + d3 * d3) * (1.0f / 256.0f);
    float r = rsqrtf(var + LN_EPS);

    float4 gg = g4[lane], be = beta4[lane];
    float4 out = make_float4(d0 * r * gg.x + be.x, d1 * r * gg.y + be.y,
                             d2 * r * gg.z + be.z, d3 * r * gg.w + be.w);
    h0[(size_t)n * 64 + lane]  = out;
    cur[(size_t)n * 64 + lane] = out;
}

// ---------------- gather (column-quarter, XCD-partitioned, 4-edge-groups x4 unroll) ----------------
// VERIFIED r8: quarter partition makes per-XCD working set L2-resident (FETCH 121->13.4 MB).
__global__ __launch_bounds__(256) void gather_q_kernel(const float4* __restrict__ m4,
                                                       const float* __restrict__ dinv,
                                                       const int* __restrict__ offs,
                                                       const int* __restrict__ csr_src,
                                                       const float4* __restrict__ bias4,
                                                       float4* __restrict__ pre4) {
    int i  = blockIdx.x;
    int q  = (i & 7) >> 1;
    int nb = (i >> 3) * 2 + (i & 1);
    int n  = nb * 4 + (threadIdx.x >> 6);
    int lane = threadIdx.x & 63;
    int g = lane >> 4;                 // edge-group 0..3
    int t = lane & 15;                 // float4 slot within the 64-col quarter
    int cbase = q * 16 + t;            // float4 index within the 64-float4 row

    float dn = dinv[n];

    float4 acc = make_float4(0.f, 0.f, 0.f, 0.f);
    if (g == 0) {                      // self loop, norm = 1/deg
        float4 sv = m4[(size_t)n * 64 + cbase];
        float dn2 = dn * dn;
        acc.x = sv.x * dn2; acc.y = sv.y * dn2; acc.z = sv.z * dn2; acc.w = sv.w * dn2;
    }

    int e1 = offs[n + 1];
    int ee = offs[n] + g;
    for (; ee + 12 < e1; ee += 16) {   // 4 edges per group per iteration
        int sA = csr_src[ee];
        int sB = csr_src[ee + 4];
        int sC = csr_src[ee + 8];
        int sD = csr_src[ee + 12];
        float4 vA = m4[(size_t)sA * 64 + cbase];
        float4 vB = m4[(size_t)sB * 64 + cbase];
        float4 vC = m4[(size_t)sC * 64 + cbase];
        float4 vD = m4[(size_t)sD * 64 + cbase];
        float wA = dinv[sA] * dn;
        float wB = dinv[sB] * dn;
        float wC = dinv[sC] * dn;
        float wD = dinv[sD] * dn;
        acc.x += wA * vA.x + wB * vB.x + wC * vC.x + wD * vD.x;
        acc.y += wA * vA.y + wB * vB.y + wC * vC.y + wD * vD.y;
        acc.z += wA * vA.z + wB * vB.z + wC * vC.z + wD * vD.z;
        acc.w += wA * vA.w + wB * vB.w + wC * vC.w + wD * vD.w;
    }
    for (; ee < e1; ee += 4) {
        int s = csr_src[ee];
        float4 v = m4[(size_t)s * 64 + cbase];
        float w = dinv[s] * dn;
        acc.x += w * v.x; acc.y += w * v.y; acc.z += w * v.z; acc.w += w * v.w;
    }

    acc.x += __shfl_xor(acc.x, 16);
    acc.y += __shfl_xor(acc.y, 16);
    acc.z += __shfl_xor(acc.z, 16);
    acc.w += __shfl_xor(acc.w, 16);
    acc.x += __shfl_xor(acc.x, 32);
    acc.y += __shfl_xor(acc.y, 32);
    acc.z += __shfl_xor(acc.z, 32);
    acc.w += __shfl_xor(acc.w, 32);

    if (g == 0) {
        float4 bb = bias4[cbase];
        pre4[(size_t)n * 64 + cbase] = make_float4(acc.x + bb.x, acc.y + bb.y,
                                                   acc.z + bb.z, acc.w + bb.w);
    }
}

// ---------------- GELU + LN + residual (reads pre, updates cur in place) ----------------
__global__ __launch_bounds__(256) void ln_res_kernel(const float4* __restrict__ pre4,
                                                     const float4* __restrict__ g4,
                                                     const float4* __restrict__ beta4,
                                                     const float4* __restrict__ h04,
                                                     float4* __restrict__ cur4) {
    int n = blockIdx.x * 4 + (threadIdx.x >> 6);
    int lane = threadIdx.x & 63;
    if (n >= N_NODES) return;

    float4 v = pre4[(size_t)n * 64 + lane];   // bias already included
    float x0 = gelu_exact(v.x);
    float x1 = gelu_exact(v.y);
    float x2 = gelu_exact(v.z);
    float x3 = gelu_exact(v.w);

    float mu = wave_sum64(x0 + x1 + x2 + x3) * (1.0f / 256.0f);
    float d0 = x0 - mu, d1 = x1 - mu, d2 = x2 - mu, d3 = x3 - mu;
    float var = wave_sum64(d0 * d0 + d1 * d1 + d2 * d2 + d3 * d3) * (1.0f / 256.0f);
    float r = rsqrtf(var + LN_EPS);

    float4 gg = g4[lane], be = beta4[lane];
    float h0v = d0 * r * gg.x + be.x;
    float h1v = d1 * r * gg.y + be.y;
    float h2v = d2 * r * gg.z + be.z;
    float h3v = d3 * r * gg.w + be.w;

    size_t idx = (size_t)n * 64 + lane;
    float4 c = cur4[idx];
    float4 h = h04[idx];
    float4 o = make_float4(c.x + (1.0f - ALPHA) * h0v + ALPHA * h.x,
                           c.y + (1.0f - ALPHA) * h1v + ALPHA * h.y,
                           c.z + (1.0f - ALPHA) * h2v + ALPHA * h.z,
                           c.w + (1.0f - ALPHA) * h3v + ALPHA * h.w);
    cur4[idx] = o;
}

// ---------------- launcher ----------------

extern "C" void kernel_launch(void* const* d_in, const int* in_sizes, int n_in,
                              void* d_out, int out_size, void* d_ws, size_t ws_size,
                              hipStream_t stream) {
    const float* x      = (const float*)d_in[0];
    const int*   ei     = (const int*)  d_in[1];   // (2, E): [0]=src, [1]=dst
    const float* W_in   = (const float*)d_in[2];
    const float* b_in   = (const float*)d_in[3];
    const float* g_in   = (const float*)d_in[4];
    const float* bt_in  = (const float*)d_in[5];
    const float* Wl     = (const float*)d_in[6];   // (L, 256, 256)
    const float* bl     = (const float*)d_in[7];
    const float* gl     = (const float*)d_in[8];
    const float* betal  = (const float*)d_in[9];

    const int* src = ei;
    const int* dst = ei + N_EDGES;

    float* cur = (float*)d_out;

    char* w = (char*)d_ws;
    size_t off = 0;
    auto alloc = [&](size_t bytes) -> void* {
        void* p = w + off;
        off = (off + bytes + 255) & ~(size_t)255;
        return p;
    };
    const size_t WT_ELEMS = (size_t)6 * HIDDEN * HIDDEN + (size_t)HIDDEN * IN_DIM;  // 425984
    int*   cnt      = (int*)  alloc(N_NODES * sizeof(int));
    int*   cursor   = (int*)  alloc(N_NODES * sizeof(int));
    int*   offs     = (int*)  alloc((N_NODES + 1) * sizeof(int));
    float* dinv     = (float*)alloc(N_NODES * sizeof(float));
    int*   csr_src  = (int*)  alloc(N_EDGES * sizeof(int));
    float* h0       = (float*)alloc((size_t)N_NODES * HIDDEN * sizeof(float));
    float* m        = (float*)alloc((size_t)N_NODES * HIDDEN * sizeof(float));
    float* pre      = (float*)alloc((size_t)N_NODES * HIDDEN * sizeof(float));
    unsigned short* wt_hi = (unsigned short*)alloc(WT_ELEMS * sizeof(unsigned short));
    unsigned short* wt_lo = (unsigned short*)alloc(WT_ELEMS * sizeof(unsigned short));

    hipMemsetAsync(cnt,    0, N_NODES * sizeof(int), stream);
    hipMemsetAsync(cursor, 0, N_NODES * sizeof(int), stream);

    const int EB = (N_EDGES + 255) / 256;
    const int NB = (N_NODES + 255) / 256;
    const int NODE_BLOCKS = (N_NODES + 3) / 4;   // 2500

    count_deg_kernel<<<EB, 256, 0, stream>>>(dst, cnt);
    dinv_kernel<<<NB, 256, 0, stream>>>(cnt, dinv);
    scan_kernel<<<1, 256, 0, stream>>>(cnt, offs);
    fill_csr_kernel<<<EB, 256, 0, stream>>>(src, dst, offs, cursor, csr_src);

    // weight transpose + bf16 hi/lo split (once per call)
    prep_w_kernel<<<dim3(8, 8, 7), 256, 0, stream>>>(Wl, W_in, wt_hi, wt_lo);

    dim3 ggrid((N_NODES + 63) / 64, HIDDEN / 64);   // 157 x 4

    const size_t IN_OFF = (size_t)6 * HIDDEN * HIDDEN;
    gemm_mfma_kernel<IN_DIM><<<ggrid, 256, 0, stream>>>(x, wt_hi + IN_OFF, wt_lo + IN_OFF, m);
    ln_in_kernel<<<NODE_BLOCKS, 256, 0, stream>>>((const float4*)m, (const float4*)b_in,
                                                  (const float4*)g_in, (const float4*)bt_in,
                                                  (float4*)h0, (float4*)cur);

    for (int l = 0; l < NUM_LAYERS; ++l) {
        gemm_mfma_kernel<HIDDEN><<<ggrid, 256, 0, stream>>>(cur,
                                                            wt_hi + (size_t)l * HIDDEN * HIDDEN,
                                                            wt_lo + (size_t)l * HIDDEN * HIDDEN,
                                                            m);
        gather_q_kernel<<<NODE_BLOCKS * 4, 256, 0, stream>>>((const float4*)m, dinv, offs, csr_src,
                                                             (const float4*)(bl + l * HIDDEN),
                                                             (float4*)pre);
        ln_res_kernel<<<NODE_BLOCKS, 256, 0, stream>>>((const float4*)pre,
                                                       (const float4*)(gl + l * HIDDEN),
                                                       (const float4*)(betal + l * HIDDEN),
                                                       (const float4*)h0, (float4*)cur);
    }
}